// Round 9
// baseline (4701.696 us; speedup 1.0000x reference)
//
#include <hip/hip_runtime.h>
#include <hip/hip_bf16.h>
#include <stddef.h>
#include <stdint.h>

#define T_STEPS 512
#define B_SZ 256
#define H_SZ 256
#define G4H 1024  // 4*H
#define PH 264            // Hs row pitch in shorts (+8 pad: conflict-free af reads)
#define HS_PAR (16 * PH)  // shorts per h parity buffer
#define NPROD 240         // producer blocks (16..255)
#define CHUNK 16          // handshake granularity (steps); T_STEPS/CHUNK = 32
#define NCHUNK (T_STEPS / CHUNK)
#define STEP_SHORTS ((size_t)16 * 1024 * 16)  // xg shorts per step (512 KB)

#define LOG2E 1.4426950408889634f
#define TWO_LOG2E 2.8853900817779268f

typedef __attribute__((ext_vector_type(8))) short bf16x8;
typedef __attribute__((ext_vector_type(4))) float f32x4;

__device__ __forceinline__ unsigned short f2bf(float f) {
  union { float f; unsigned u; } v; v.f = f;
  unsigned r = v.u + 0x7fffu + ((v.u >> 16) & 1u);
  return (unsigned short)(r >> 16);
}
__device__ __forceinline__ float bf2f(unsigned short h) {
  union { unsigned u; float f; } v; v.u = ((unsigned)h) << 16; return v.f;
}
// raw HW ops: v_exp_f32 (2^x) and v_rcp_f32 — avoids ocml div/exp expansion
__device__ __forceinline__ float exp2_hw(float x) { return __builtin_amdgcn_exp2f(x); }
__device__ __forceinline__ float rcp_hw(float x) { return __builtin_amdgcn_rcpf(x); }

// producer/consumer handshake counters (zeroed by prep each launch; module-scope
// device memory: no workspace cost, graph-capture safe).
// prod_flags[c]==16 : all 16 steps of chunk c written & published (release)
// cons_flags[c]==16 : all 16 consumer blocks finished reading chunk c
__device__ int prod_flags[NCHUNK];
__device__ int cons_flags[NCHUNK];

// ---------------- prep: fp32->bf16 weights (PRESCALED), bias sum, state init ----
// Gates i,f,o scaled by log2e; gate g by 2*log2e -> activations are bare 2^x:
//   sigmoid(z) = rcp(1 + 2^-z'), tanh(g) = (2^g'' - 1) * rcp(2^g'' + 1).
__global__ void prep_kernel(const float* __restrict__ h0, const float* __restrict__ c0,
                            const float* __restrict__ W_ih, const float* __restrict__ W_hh,
                            const float* __restrict__ b_ih, const float* __restrict__ b_hh,
                            unsigned short* __restrict__ Wih_bf, unsigned short* __restrict__ Whh_bf,
                            float* __restrict__ bias, unsigned short* __restrict__ h_st,
                            float* __restrict__ c_st) {
  int i = blockIdx.x * 256 + threadIdx.x;
  int stride = gridDim.x * 256;
  for (int k = i; k < NCHUNK; k += stride) {
    prod_flags[k] = 0;
    cons_flags[k] = 0;
  }
  for (int k = i; k < G4H * H_SZ; k += stride) {
    int gate = k >> 16;  // row = k>>8, gate = row>>8
    float sc = (gate == 2) ? TWO_LOG2E : LOG2E;
    Wih_bf[k] = f2bf(W_ih[k] * sc);
    Whh_bf[k] = f2bf(W_hh[k] * sc);
  }
  for (int k = i; k < B_SZ * H_SZ; k += stride) {
    h_st[k] = f2bf(h0[k]);
    c_st[k] = c0[k];
  }
  for (int k = i; k < G4H; k += stride) {
    float sc = ((k >> 8) == 2) ? TWO_LOG2E : LOG2E;
    bias[k] = (b_ih[k] + b_hh[k]) * sc;
  }
}

// ---------------- serial fallback K1 (r8-proven): one block per 64-row tile.
__global__ __launch_bounds__(256, 2) void xgate_kernel(
    const int* __restrict__ enc, const float* __restrict__ embed,
    const unsigned short* __restrict__ Wih_bf, const float* __restrict__ bias,
    unsigned short* __restrict__ xg, int t0, int Ci) {
  __shared__ __align__(16) unsigned short As[64][264];
  const int tid = threadIdx.x;
  const int mbase = blockIdx.x * 64;

  {
    int r = tid >> 2, q = tid & 3;
    int mg = mbase + r;
    int s = mg >> 8, b = mg & 255;
    int vid = enc[(t0 + s) * B_SZ + b];
    const float4* src = (const float4*)(embed + (size_t)vid * H_SZ) + q * 16;
#pragma unroll
    for (int j = 0; j < 16; ++j) {
      float4 x = src[j];
      ushort4 o;
      o.x = f2bf(x.x); o.y = f2bf(x.y); o.z = f2bf(x.z); o.w = f2bf(x.w);
      *(ushort4*)&As[r][q * 64 + j * 4] = o;
    }
  }
  __syncthreads();

  const int wave = tid >> 6, lane = tid & 63;
  const int lrow = lane & 15, quad = lane >> 4;

  bf16x8 af[4][8];
#pragma unroll
  for (int mt = 0; mt < 4; ++mt)
#pragma unroll
    for (int ks = 0; ks < 8; ++ks)
      af[mt][ks] = *(const bf16x8*)&As[mt * 16 + lrow][ks * 32 + quad * 8];

  const int t_loc = mbase >> 8;

  for (int g = 0; g < 4; ++g) {
#pragma unroll
    for (int nt = 0; nt < 4; ++nt) {
      const int j = wave * 64 + nt * 16 + lrow;
      const int nrow = g * 256 + j;
      const unsigned short* wrow = Wih_bf + (size_t)nrow * H_SZ + quad * 8;
      bf16x8 bf[8];
#pragma unroll
      for (int ks = 0; ks < 8; ++ks) bf[ks] = *(const bf16x8*)(wrow + ks * 32);
      const float bs = bias[nrow];
#pragma unroll
      for (int mt = 0; mt < 4; ++mt) {
        f32x4 a = {0.f, 0.f, 0.f, 0.f};
#pragma unroll
        for (int ks = 0; ks < 8; ++ks)
          a = __builtin_amdgcn_mfma_f32_16x16x32_bf16(af[mt][ks], bf[ks], a, 0, 0, 0);
        const int bg = ((mbase >> 4) & 15) + mt;
        const int tid2 = (wave * 4 + nt) * 64 + quad * 16 + lrow;
        const size_t off = (((size_t)t_loc * 16 + bg) * 1024 + tid2) * 16 + g * 4;
        ushort4 o;
        o.x = f2bf(a[0] + bs); o.y = f2bf(a[1] + bs);
        o.z = f2bf(a[2] + bs); o.w = f2bf(a[3] + bs);
        *(ushort4*)(xg + off) = o;
      }
    }
  }
}

// ---------------- serial fallback K2 (r8-proven lstm, verbatim).
__global__ __launch_bounds__(1024) void lstm_kernel(
    const unsigned short* __restrict__ Whh_bf, const unsigned short* __restrict__ xg,
    unsigned short* __restrict__ h_st, float* __restrict__ c_st,
    float* __restrict__ out, int t0, int Ci) {
  __shared__ __align__(16) unsigned short Hs[2 * HS_PAR];
  __shared__ __align__(16) unsigned short Wg[16 * 4096];

  const int tid = threadIdx.x, w = tid >> 6, lane = tid & 63;
  const int lrow = lane & 15, quad = lane >> 4;
  const int b0 = blockIdx.x * 16;
  const int jcol = w * 16 + lrow;

  bf16x8 wf0[8], wf1[8];
  {
    const unsigned short* wr0 = Whh_bf + (size_t)(0 * 256 + jcol) * H_SZ + quad * 8;
    const unsigned short* wr1 = Whh_bf + (size_t)(1 * 256 + jcol) * H_SZ + quad * 8;
#pragma unroll
    for (int ks = 0; ks < 8; ++ks) {
      wf0[ks] = *(const bf16x8*)(wr0 + ks * 32);
      wf1[ks] = *(const bf16x8*)(wr1 + ks * 32);
    }
  }
  {
    const unsigned short* wr2 = Whh_bf + (size_t)(2 * 256 + jcol) * H_SZ + quad * 8;
#pragma unroll
    for (int ks = 0; ks < 8; ++ks) {
      bf16x8 v = *(const bf16x8*)(wr2 + ks * 32);
      *(bf16x8*)&Wg[w * 4096 + ks * 512 + lane * 8] = v;
    }
  }
  const unsigned short* wr3 = Whh_bf + (size_t)(3 * 256 + jcol) * H_SZ + quad * 8;

  if (tid < 256) {
    int row = tid >> 4, c16 = (tid & 15) * 16;
    const unsigned short* src = h_st + (size_t)(b0 + row) * H_SZ + c16;
    *(uint4*)&Hs[row * PH + c16] = *(const uint4*)src;
    *(uint4*)&Hs[row * PH + c16 + 8] = *(const uint4*)(src + 8);
  }

  float creg[4], hv[4];
#pragma unroll
  for (int r = 0; r < 4; ++r)
    creg[r] = c_st[(size_t)(b0 + quad * 4 + r) * H_SZ + jcol];

  const unsigned short* pxg = xg + ((size_t)blockIdx.x * 1024 + tid) * 16;
  uint4 xa0 = *(const uint4*)pxg;
  uint4 xa1 = *(const uint4*)(pxg + 8);
  __syncthreads();

  const int af_base = lrow * (PH * 2) + quad * 16;
  const int hw_base = (quad * 4) * (PH * 2) + jcol * 2;
  const int PAR_B = HS_PAR * 2;
  const unsigned short* wlds = &Wg[w * 4096 + lane * 8];

#pragma unroll 1
  for (int s = 0; s < Ci; ++s) {
    const int rp = (s & 1) * PAR_B;
    const int wp = PAR_B - rp;
    const char* hsr = (const char*)Hs + af_base + rp;
    char* hsw = (char*)Hs + hw_base + wp;

    f32x4 a0 = {0.f, 0.f, 0.f, 0.f}, a2 = a0;
#pragma unroll
    for (int ks = 0; ks < 8; ++ks) {
      bf16x8 af = *(const bf16x8*)(hsr + ks * 64);
      bf16x8 w2 = *(const bf16x8*)(wlds + ks * 512);
      a0 = __builtin_amdgcn_mfma_f32_16x16x32_bf16(af, wf0[ks], a0, 0, 0, 0);
      a2 = __builtin_amdgcn_mfma_f32_16x16x32_bf16(af, w2, a2, 0, 0, 0);
    }

    pxg += (size_t)((s + 1 < Ci) ? 16 * 1024 * 16 : 0);
    uint4 xb0 = *(const uint4*)pxg;
    uint4 xb1 = *(const uint4*)(pxg + 8);

    const unsigned short* xv0 = (const unsigned short*)&xa0;
    const unsigned short* xv1 = (const unsigned short*)&xa1;
    float ig[4];
#pragma unroll
    for (int r = 0; r < 4; ++r) {
      float zi = a0[r] + bf2f(xv0[r]);
      float zg = a2[r] + bf2f(xv1[r]);
      float ei = exp2_hw(-zi);
      float eg = exp2_hw(zg);
      ig[r] = (eg - 1.0f) * rcp_hw((1.0f + ei) * (eg + 1.0f));
    }

    f32x4 a1 = {0.f, 0.f, 0.f, 0.f}, a3 = a1;
#pragma unroll
    for (int ks = 0; ks < 8; ++ks) {
      bf16x8 af = *(const bf16x8*)(hsr + ks * 64);
      bf16x8 w3 = *(const bf16x8*)(wr3 + ks * 32);
      a1 = __builtin_amdgcn_mfma_f32_16x16x32_bf16(af, wf1[ks], a1, 0, 0, 0);
      a3 = __builtin_amdgcn_mfma_f32_16x16x32_bf16(af, w3, a3, 0, 0, 0);
    }

#pragma unroll
    for (int r = 0; r < 4; ++r) {
      float zf = a1[r] + bf2f(xv0[4 + r]);
      float zo = a3[r] + bf2f(xv1[4 + r]);
      float ef = exp2_hw(-zf);
      float c = fmaf(creg[r], rcp_hw(1.0f + ef), ig[r]);
      creg[r] = c;
      float eo = exp2_hw(-zo);
      float ec = exp2_hw(fminf(c * TWO_LOG2E, 126.0f));
      float h = (ec - 1.0f) * rcp_hw((1.0f + eo) * (ec + 1.0f));
      hv[r] = h;
      *(unsigned short*)(hsw + r * (PH * 2)) = f2bf(h);
    }
    xa0 = xb0;
    xa1 = xb1;
    __syncthreads();
  }

#pragma unroll
  for (int r = 0; r < 4; ++r) {
    const size_t gidx = (size_t)(b0 + quad * 4 + r) * H_SZ + jcol;
    h_st[gidx] = f2bf(hv[r]);
    c_st[gidx] = creg[r];
  }
  if (t0 + Ci == T_STEPS) {
#pragma unroll
    for (int r = 0; r < 4; ++r) {
      const size_t gidx = (size_t)(b0 + quad * 4 + r) * H_SZ + jcol;
      out[gidx] = hv[r];
      out[(size_t)B_SZ * H_SZ + gidx] = creg[r];
    }
  }
}

// ---------------- fused: 256 blocks x 1024 threads, 1 block/CU, ALL resident
// (LDS 148 KB -> 1 block/CU; VGPR <=128 -> 4 waves/SIMD). xg is a RING of R
// steps (R from ws_size, multiple of CHUNK — r7's crash was writing 256 MB of
// absolute-indexed xg into a ~38 MB workspace; slot = s % R fixes it).
// Blocks 0..15   consumers: verbatim r1 lstm; per 16-step chunk: publish
//                prev chunk consumed (release), spin-acquire prod_flags, reload
//                ring pointer. Mid-step prefetch suppressed at boundaries.
// Blocks 16..255 producers: block p does steps {p, p+240, p+480}; waits for
//                slot (s-R) consumed before writing; publishes after
//                __syncthreads (vmcnt drain) + threadfence + release-add.
// Deadlock-free: all 256 blocks co-resident; producers start R>=32 steps ahead
// of any wait; dependency graph is acyclic chunk-by-chunk.
__global__ __launch_bounds__(1024) void fused_kernel(
    const int* __restrict__ enc, const float* __restrict__ embed,
    const unsigned short* __restrict__ Wih_bf, const float* __restrict__ bias,
    const unsigned short* __restrict__ Whh_bf, unsigned short* __restrict__ xg,
    unsigned short* __restrict__ h_st, float* __restrict__ c_st,
    float* __restrict__ out, int R) {
  __shared__ __align__(16) unsigned char smem[147968];
  const int blk = blockIdx.x;
  const int tid = threadIdx.x;

  if (blk >= 16) {
    // ================= PRODUCER =================
    const int p = blk - 16;  // 0..239
    const int t256 = tid & 255, unit = tid >> 8;
    unsigned short* AsU = (unsigned short*)(smem + unit * 33792);  // [64][264]
    const int wave = t256 >> 6, lane = tid & 63;
    const int lrow = lane & 15, quad = lane >> 4;

#pragma unroll 1
    for (int s = p; s < T_STEPS; s += NPROD) {
      // stage As: 64 rows of embed (gather), fp32 -> bf16
      {
        int r = t256 >> 2, q = t256 & 3;
        int b = unit * 64 + r;
        int vid = enc[s * B_SZ + b];
        const float4* src = (const float4*)(embed + (size_t)vid * H_SZ) + q * 16;
#pragma unroll
        for (int j = 0; j < 16; ++j) {
          float4 x = src[j];
          ushort4 o;
          o.x = f2bf(x.x); o.y = f2bf(x.y); o.z = f2bf(x.z); o.w = f2bf(x.w);
          *(ushort4*)&AsU[r * 264 + q * 64 + j * 4] = o;
        }
      }
      // ring pacing: slot (s % R) free only when step s-R fully consumed
      if (tid == 0) {
        int sprev = s - R;
        if (sprev >= 0) {
          while (__hip_atomic_load(&cons_flags[sprev >> 4], __ATOMIC_ACQUIRE,
                                   __HIP_MEMORY_SCOPE_AGENT) < 16)
            __builtin_amdgcn_s_sleep(8);
        }
      }
      __syncthreads();  // As staged AND slot free

      const size_t slot = (size_t)(s % R);
#pragma unroll 1
      for (int mt = 0; mt < 4; ++mt) {
        bf16x8 af[8];
#pragma unroll
        for (int ks = 0; ks < 8; ++ks)
          af[ks] = *(const bf16x8*)&AsU[(mt * 16 + lrow) * 264 + ks * 32 + quad * 8];
#pragma unroll 1
        for (int nt = 0; nt < 4; ++nt) {
          const int j = wave * 64 + nt * 16 + lrow;  // hidden column
          f32x4 acc[4];
          float bs[4];
#pragma unroll
          for (int g = 0; g < 4; ++g) {
            const int nrow = g * 256 + j;
            const unsigned short* wrow = Wih_bf + (size_t)nrow * H_SZ + quad * 8;
            bf16x8 bfr[8];
#pragma unroll
            for (int ks = 0; ks < 8; ++ks) bfr[ks] = *(const bf16x8*)(wrow + ks * 32);
            bs[g] = bias[nrow];
            f32x4 a = {0.f, 0.f, 0.f, 0.f};
#pragma unroll
            for (int ks = 0; ks < 8; ++ks)
              a = __builtin_amdgcn_mfma_f32_16x16x32_bf16(af[ks], bfr[ks], a, 0, 0, 0);
            acc[g] = a;
          }
          const int bg = unit * 4 + mt;
          const int tid2 = (wave * 4 + nt) * 64 + quad * 16 + lrow;
          const size_t off = ((slot * 16 + bg) * 1024 + tid2) * 16;
          unsigned short ov[16];
#pragma unroll
          for (int g = 0; g < 4; ++g)
#pragma unroll
            for (int r = 0; r < 4; ++r) ov[g * 4 + r] = f2bf(acc[g][r] + bs[g]);
          *(uint4*)(xg + off) = *(const uint4*)&ov[0];
          *(uint4*)(xg + off + 8) = *(const uint4*)&ov[8];
        }
      }
      __syncthreads();  // every wave's stores vmcnt-drained (in L2); AsU reusable
      if (tid == 0) {
        __threadfence();  // flush to device coherence point (cross-XCD visibility)
        __hip_atomic_fetch_add(&prod_flags[s >> 4], 1, __ATOMIC_RELEASE,
                               __HIP_MEMORY_SCOPE_AGENT);
      }
    }
    return;
  }

  // ================= CONSUMER (r1 lstm hot loop + chunk handshake) =========
  unsigned short* Hs = (unsigned short*)smem;            // 2*HS_PAR shorts
  unsigned short* Wg = (unsigned short*)(smem + 16896);  // 16*4096 shorts

  const int w = tid >> 6, lane = tid & 63;
  const int lrow = lane & 15, quad = lane >> 4;
  const int b0 = blk * 16;
  const int jcol = w * 16 + lrow;

  bf16x8 wf0[8], wf1[8];
  {
    const unsigned short* wr0 = Whh_bf + (size_t)(0 * 256 + jcol) * H_SZ + quad * 8;
    const unsigned short* wr1 = Whh_bf + (size_t)(1 * 256 + jcol) * H_SZ + quad * 8;
#pragma unroll
    for (int ks = 0; ks < 8; ++ks) {
      wf0[ks] = *(const bf16x8*)(wr0 + ks * 32);
      wf1[ks] = *(const bf16x8*)(wr1 + ks * 32);
    }
  }
  {
    const unsigned short* wr2 = Whh_bf + (size_t)(2 * 256 + jcol) * H_SZ + quad * 8;
#pragma unroll
    for (int ks = 0; ks < 8; ++ks) {
      bf16x8 v = *(const bf16x8*)(wr2 + ks * 32);
      *(bf16x8*)&Wg[w * 4096 + ks * 512 + lane * 8] = v;
    }
  }
  const unsigned short* wr3 = Whh_bf + (size_t)(3 * 256 + jcol) * H_SZ + quad * 8;

  if (tid < 256) {
    int row = tid >> 4, c16 = (tid & 15) * 16;
    const unsigned short* src = h_st + (size_t)(b0 + row) * H_SZ + c16;
    *(uint4*)&Hs[row * PH + c16] = *(const uint4*)src;
    *(uint4*)&Hs[row * PH + c16 + 8] = *(const uint4*)(src + 8);
  }

  float creg[4], hv[4];
#pragma unroll
  for (int r = 0; r < 4; ++r)
    creg[r] = c_st[(size_t)(b0 + quad * 4 + r) * H_SZ + jcol];

  const unsigned short* pxg = xg;
  uint4 xa0 = {0, 0, 0, 0}, xa1 = {0, 0, 0, 0};
  __syncthreads();

  const int af_base = lrow * (PH * 2) + quad * 16;
  const int hw_base = (quad * 4) * (PH * 2) + jcol * 2;
  const int PAR_B = HS_PAR * 2;
  const unsigned short* wlds = &Wg[w * 4096 + lane * 8];

#pragma unroll 1
  for (int s = 0; s < T_STEPS; ++s) {
    // chunk boundary: publish previous chunk consumed, wait for this chunk
    if ((s & (CHUNK - 1)) == 0) {
      if (tid == 0) {
        if (s > 0)
          __hip_atomic_fetch_add(&cons_flags[(s >> 4) - 1], 1, __ATOMIC_RELEASE,
                                 __HIP_MEMORY_SCOPE_AGENT);
        while (__hip_atomic_load(&prod_flags[s >> 4], __ATOMIC_ACQUIRE,
                                 __HIP_MEMORY_SCOPE_AGENT) < 16)
          __builtin_amdgcn_s_sleep(8);
      }
      __syncthreads();
      pxg = xg + (size_t)(s % R) * STEP_SHORTS + ((size_t)blk * 1024 + tid) * 16;
      xa0 = *(const uint4*)pxg;
      xa1 = *(const uint4*)(pxg + 8);
    }

    const int rp = (s & 1) * PAR_B;
    const int wp = PAR_B - rp;
    const char* hsr = (const char*)Hs + af_base + rp;
    char* hsw = (char*)Hs + hw_base + wp;

    // ---- phase 1: gates i (regs) and g (LDS) ----
    f32x4 a0 = {0.f, 0.f, 0.f, 0.f}, a2 = a0;
#pragma unroll
    for (int ks = 0; ks < 8; ++ks) {
      bf16x8 af = *(const bf16x8*)(hsr + ks * 64);
      bf16x8 w2 = *(const bf16x8*)(wlds + ks * 512);
      a0 = __builtin_amdgcn_mfma_f32_16x16x32_bf16(af, wf0[ks], a0, 0, 0, 0);
      a2 = __builtin_amdgcn_mfma_f32_16x16x32_bf16(af, w2, a2, 0, 0, 0);
    }

    // ---- mid-step prefetch (suppressed across chunk boundaries) ----
    pxg += STEP_SHORTS;
    uint4 xb0 = xa0, xb1 = xa1;
    if (((s + 1) & (CHUNK - 1)) != 0) {  // wave-uniform; false at s+1==512 too
      xb0 = *(const uint4*)pxg;
      xb1 = *(const uint4*)(pxg + 8);
    }

    // ---- sigma(i)*tanh(g), fused rcp ----
    const unsigned short* xv0 = (const unsigned short*)&xa0;  // gates i,f
    const unsigned short* xv1 = (const unsigned short*)&xa1;  // gates g,o
    float ig[4];
#pragma unroll
    for (int r = 0; r < 4; ++r) {
      float zi = a0[r] + bf2f(xv0[r]);
      float zg = a2[r] + bf2f(xv1[r]);
      float ei = exp2_hw(-zi);
      float eg = exp2_hw(zg);
      ig[r] = (eg - 1.0f) * rcp_hw((1.0f + ei) * (eg + 1.0f));
    }

    // ---- phase 2: gates f (regs) and o (L2 stream) ----
    f32x4 a1 = {0.f, 0.f, 0.f, 0.f}, a3 = a1;
#pragma unroll
    for (int ks = 0; ks < 8; ++ks) {
      bf16x8 af = *(const bf16x8*)(hsr + ks * 64);
      bf16x8 w3 = *(const bf16x8*)(wr3 + ks * 32);
      a1 = __builtin_amdgcn_mfma_f32_16x16x32_bf16(af, wf1[ks], a1, 0, 0, 0);
      a3 = __builtin_amdgcn_mfma_f32_16x16x32_bf16(af, w3, a3, 0, 0, 0);
    }

    // ---- c/h epilogue ----
#pragma unroll
    for (int r = 0; r < 4; ++r) {
      float zf = a1[r] + bf2f(xv0[4 + r]);
      float zo = a3[r] + bf2f(xv1[4 + r]);
      float ef = exp2_hw(-zf);
      float c = fmaf(creg[r], rcp_hw(1.0f + ef), ig[r]);
      creg[r] = c;
      float eo = exp2_hw(-zo);
      float ec = exp2_hw(fminf(c * TWO_LOG2E, 126.0f));
      float h = (ec - 1.0f) * rcp_hw((1.0f + eo) * (ec + 1.0f));
      hv[r] = h;
      *(unsigned short*)(hsw + r * (PH * 2)) = f2bf(h);
    }
    xa0 = xb0;
    xa1 = xb1;
    __syncthreads();
  }

  // persist state; final output
#pragma unroll
  for (int r = 0; r < 4; ++r) {
    const size_t gidx = (size_t)(b0 + quad * 4 + r) * H_SZ + jcol;
    h_st[gidx] = f2bf(hv[r]);
    c_st[gidx] = creg[r];
    out[gidx] = hv[r];
    out[(size_t)B_SZ * H_SZ + gidx] = creg[r];
  }
}

extern "C" void kernel_launch(void* const* d_in, const int* in_sizes, int n_in,
                              void* d_out, int out_size, void* d_ws, size_t ws_size,
                              hipStream_t stream) {
  const int* enc = (const int*)d_in[0];
  const float* h0 = (const float*)d_in[1];
  const float* c0 = (const float*)d_in[2];
  const float* embed = (const float*)d_in[3];
  const float* W_ih = (const float*)d_in[4];
  const float* W_hh = (const float*)d_in[5];
  const float* b_ih = (const float*)d_in[6];
  const float* b_hh = (const float*)d_in[7];
  float* out = (float*)d_out;

  char* ws = (char*)d_ws;
  unsigned short* Wih_bf = (unsigned short*)(ws);                  // 512 KB
  unsigned short* Whh_bf = (unsigned short*)(ws + (512 << 10));    // 512 KB
  float* bias = (float*)(ws + (1024 << 10));                       // 4 KB
  unsigned short* h_st = (unsigned short*)(ws + (1028 << 10));     // 128 KB
  float* c_st = (float*)(ws + (1156 << 10));                       // 256 KB
  const size_t fixed = (size_t)(1412) << 10;
  unsigned short* xg = (unsigned short*)(ws + fixed);

  const size_t per_step = (size_t)B_SZ * G4H * 2;  // 512 KB per timestep (bf16)
  int R = 0;
  if (ws_size > fixed + per_step) {
    size_t r = (ws_size - fixed) / per_step;
    R = (r > T_STEPS) ? T_STEPS : (int)r;
  }

  prep_kernel<<<dim3(256), dim3(256), 0, stream>>>(h0, c0, W_ih, W_hh, b_ih, b_hh,
                                                   Wih_bf, Whh_bf, bias, h_st, c_st);

  int Rring = R & ~(CHUNK - 1);  // multiple of CHUNK: chunk slots stay contiguous
  if (Rring >= 2 * CHUNK) {
    // fused producer-consumer path: xg ring of Rring steps fits the workspace
    fused_kernel<<<dim3(256), dim3(1024), 0, stream>>>(enc, embed, Wih_bf, bias,
                                                       Whh_bf, xg, h_st, c_st, out,
                                                       Rring);
  } else {
    // serial fallback (proven r1/r8 path)
    int C = (R > 0) ? R : 1;
    for (int t0 = 0; t0 < T_STEPS; t0 += C) {
      int Ci = (T_STEPS - t0 < C) ? (T_STEPS - t0) : C;
      xgate_kernel<<<dim3(Ci * 4), dim3(256), 0, stream>>>(enc, embed, Wih_bf, bias,
                                                           xg, t0, Ci);
      lstm_kernel<<<dim3(16), dim3(1024), 0, stream>>>(Whh_bf, xg, h_st, c_st,
                                                       out, t0, Ci);
    }
  }
}

// Round 10
// 2009.234 us; speedup vs baseline: 2.3400x; 2.3400x over previous
//
#include <hip/hip_runtime.h>
#include <hip/hip_bf16.h>
#include <stddef.h>
#include <stdint.h>

#define T_STEPS 512
#define B_SZ 256
#define H_SZ 256
#define G4H 1024  // 4*H
#define PH 264            // Hs row pitch in shorts (+8 pad: conflict-free af reads)
#define HS_PAR (16 * PH)  // shorts per h parity buffer

#define LOG2E 1.4426950408889634f
#define TWO_LOG2E 2.8853900817779268f

typedef __attribute__((ext_vector_type(8))) short bf16x8;
typedef __attribute__((ext_vector_type(4))) float f32x4;

__device__ __forceinline__ unsigned short f2bf(float f) {
  union { float f; unsigned u; } v; v.f = f;
  unsigned r = v.u + 0x7fffu + ((v.u >> 16) & 1u);
  return (unsigned short)(r >> 16);
}
__device__ __forceinline__ float bf2f(unsigned short h) {
  union { unsigned u; float f; } v; v.u = ((unsigned)h) << 16; return v.f;
}
// raw HW ops: v_exp_f32 (2^x) and v_rcp_f32 — avoids ocml div/exp expansion
__device__ __forceinline__ float exp2_hw(float x) { return __builtin_amdgcn_exp2f(x); }
__device__ __forceinline__ float rcp_hw(float x) { return __builtin_amdgcn_rcpf(x); }

// ---------------- prep: fp32->bf16 weights (PRESCALED), bias sum, state init ----
// Gates i,f,o scaled by log2e; gate g by 2*log2e. Then activations are bare 2^x:
//   sigmoid(z) = rcp(1 + 2^-z'), tanh(g) = (2^g'' - 1) * rcp(2^g'' + 1).
__global__ void prep_kernel(const float* __restrict__ h0, const float* __restrict__ c0,
                            const float* __restrict__ W_ih, const float* __restrict__ W_hh,
                            const float* __restrict__ b_ih, const float* __restrict__ b_hh,
                            unsigned short* __restrict__ Wih_bf, unsigned short* __restrict__ Whh_bf,
                            float* __restrict__ bias, unsigned short* __restrict__ h_st,
                            float* __restrict__ c_st) {
  int i = blockIdx.x * 256 + threadIdx.x;
  int stride = gridDim.x * 256;
  for (int k = i; k < G4H * H_SZ; k += stride) {
    int gate = k >> 16;  // row = k>>8, gate = row>>8
    float sc = (gate == 2) ? TWO_LOG2E : LOG2E;
    Wih_bf[k] = f2bf(W_ih[k] * sc);
    Whh_bf[k] = f2bf(W_hh[k] * sc);
  }
  for (int k = i; k < B_SZ * H_SZ; k += stride) {
    h_st[k] = f2bf(h0[k]);
    c_st[k] = c0[k];
  }
  for (int k = i; k < G4H; k += stride) {
    float sc = ((k >> 8) == 2) ? TWO_LOG2E : LOG2E;
    bias[k] = (b_ih[k] + b_hh[k]) * sc;
  }
}

// ---------------- K1: xg = bf16( embed[idx] @ W_ih^T + b ) , prescaled units.
// ONE block per 64-row tile does ALL 4 gates (A-tile staged & reused 4x).
// Output layout (for K2): flat = (((t_loc*16 + bg)*1024) + tid2)*16 + g*4 + r
__global__ __launch_bounds__(256, 2) void xgate_kernel(
    const int* __restrict__ enc, const float* __restrict__ embed,
    const unsigned short* __restrict__ Wih_bf, const float* __restrict__ bias,
    unsigned short* __restrict__ xg, int t0, int Ci) {
  __shared__ __align__(16) unsigned short As[64][264];
  const int tid = threadIdx.x;
  const int mbase = blockIdx.x * 64;

  // stage A tile: 64 rows of embed (gather), fp32 -> bf16
  {
    int r = tid >> 2, q = tid & 3;
    int mg = mbase + r;
    int s = mg >> 8, b = mg & 255;
    int vid = enc[(t0 + s) * B_SZ + b];
    const float4* src = (const float4*)(embed + (size_t)vid * H_SZ) + q * 16;
#pragma unroll
    for (int j = 0; j < 16; ++j) {
      float4 x = src[j];
      ushort4 o;
      o.x = f2bf(x.x); o.y = f2bf(x.y); o.z = f2bf(x.z); o.w = f2bf(x.w);
      *(ushort4*)&As[r][q * 64 + j * 4] = o;
    }
  }
  __syncthreads();

  const int wave = tid >> 6, lane = tid & 63;
  const int lrow = lane & 15, quad = lane >> 4;

  // A fragments fully resident: 4 m-tiles x 8 k-steps (reused for all 4 gates)
  bf16x8 af[4][8];
#pragma unroll
  for (int mt = 0; mt < 4; ++mt)
#pragma unroll
    for (int ks = 0; ks < 8; ++ks)
      af[mt][ks] = *(const bf16x8*)&As[mt * 16 + lrow][ks * 32 + quad * 8];

  const int t_loc = mbase >> 8;

  for (int g = 0; g < 4; ++g) {
#pragma unroll
    for (int nt = 0; nt < 4; ++nt) {
      const int j = wave * 64 + nt * 16 + lrow;      // hidden column
      const int nrow = g * 256 + j;                  // W_ih row
      const unsigned short* wrow = Wih_bf + (size_t)nrow * H_SZ + quad * 8;
      bf16x8 bf[8];
#pragma unroll
      for (int ks = 0; ks < 8; ++ks) bf[ks] = *(const bf16x8*)(wrow + ks * 32);
      const float bs = bias[nrow];
#pragma unroll
      for (int mt = 0; mt < 4; ++mt) {
        f32x4 a = {0.f, 0.f, 0.f, 0.f};
#pragma unroll
        for (int ks = 0; ks < 8; ++ks)
          a = __builtin_amdgcn_mfma_f32_16x16x32_bf16(af[mt][ks], bf[ks], a, 0, 0, 0);
        const int bg = ((mbase >> 4) & 15) + mt;
        const int tid2 = (wave * 4 + nt) * 64 + quad * 16 + lrow;
        const size_t off = (((size_t)t_loc * 16 + bg) * 1024 + tid2) * 16 + g * 4;
        ushort4 o;
        o.x = f2bf(a[0] + bs); o.y = f2bf(a[1] + bs);
        o.z = f2bf(a[2] + bs); o.w = f2bf(a[3] + bs);
        *(ushort4*)(xg + off) = o;
      }
    }
  }
}

// ---------------- K2: recurrent. 16 blocks x 1024 threads (16 waves, 4/SIMD).
// Block owns 16 batches; wave w owns hidden cols j = w*16..w*16+15, ALL 4 gates.
// REGISTER BUDGET: 1024-thread block => 4 waves/SIMD => 128 unified VGPR+AGPR
// per wave. Weights i,f in regs (64), gate g in LDS (128 KB), gate o streamed
// from L2 each step (wf3-in-regs spills: measured r2). TWO-PHASE step (proven
// r1/r4/r5: the split hides the w3 L2 latency under phase-1's LDS+MFMA work;
// merging phases +37%, wave-staggering +77%). Mid-step xg prefetch (1.5-step
// distance); plain __syncthreads per step (lgkmcnt-only barrier tricks are
// pointless here: waiting for the youngest w3 drains everything older anyway —
// measured r3). Producer-consumer fusion tried twice (r7 crash, r9 2.3x slower
// — consumer slowdown with producers exited; root cause unresolved): abandoned.
__global__ __launch_bounds__(1024) void lstm_kernel(
    const unsigned short* __restrict__ Whh_bf, const unsigned short* __restrict__ xg,
    unsigned short* __restrict__ h_st, float* __restrict__ c_st,
    float* __restrict__ out, int t0, int Ci) {
  __shared__ __align__(16) unsigned short Hs[2 * HS_PAR];   // 16.5 KB (double-buffered h)
  __shared__ __align__(16) unsigned short Wg[16 * 4096];    // 128 KB (gate-g fragments)

  const int tid = threadIdx.x, w = tid >> 6, lane = tid & 63;
  const int lrow = lane & 15, quad = lane >> 4;
  const int b0 = blockIdx.x * 16;
  const int jcol = w * 16 + lrow;

  // gates i,f resident in registers
  bf16x8 wf0[8], wf1[8];
  {
    const unsigned short* wr0 = Whh_bf + (size_t)(0 * 256 + jcol) * H_SZ + quad * 8;
    const unsigned short* wr1 = Whh_bf + (size_t)(1 * 256 + jcol) * H_SZ + quad * 8;
#pragma unroll
    for (int ks = 0; ks < 8; ++ks) {
      wf0[ks] = *(const bf16x8*)(wr0 + ks * 32);
      wf1[ks] = *(const bf16x8*)(wr1 + ks * 32);
    }
  }
  // gate g staged into LDS, fragment-order
  {
    const unsigned short* wr2 = Whh_bf + (size_t)(2 * 256 + jcol) * H_SZ + quad * 8;
#pragma unroll
    for (int ks = 0; ks < 8; ++ks) {
      bf16x8 v = *(const bf16x8*)(wr2 + ks * 32);
      *(bf16x8*)&Wg[w * 4096 + ks * 512 + lane * 8] = v;
    }
  }
  // gate o: streamed from global (L2) every step
  const unsigned short* wr3 = Whh_bf + (size_t)(3 * 256 + jcol) * H_SZ + quad * 8;

  // stage h into parity-0 LDS buffer
  if (tid < 256) {
    int row = tid >> 4, c16 = (tid & 15) * 16;
    const unsigned short* src = h_st + (size_t)(b0 + row) * H_SZ + c16;
    *(uint4*)&Hs[row * PH + c16] = *(const uint4*)src;
    *(uint4*)&Hs[row * PH + c16 + 8] = *(const uint4*)(src + 8);
  }

  float creg[4], hv[4];
#pragma unroll
  for (int r = 0; r < 4; ++r)
    creg[r] = c_st[(size_t)(b0 + quad * 4 + r) * H_SZ + jcol];

  // xg: 32 contiguous bytes per lane per step, prefetched one step ahead
  const unsigned short* pxg = xg + ((size_t)blockIdx.x * 1024 + tid) * 16;
  uint4 xa0 = *(const uint4*)pxg;
  uint4 xa1 = *(const uint4*)(pxg + 8);
  __syncthreads();

  const int af_base = lrow * (PH * 2) + quad * 16;
  const int hw_base = (quad * 4) * (PH * 2) + jcol * 2;
  const int PAR_B = HS_PAR * 2;  // 8448 bytes
  const unsigned short* wlds = &Wg[w * 4096 + lane * 8];

#pragma unroll 1
  for (int s = 0; s < Ci; ++s) {
    const int rp = (s & 1) * PAR_B;         // read parity
    const int wp = PAR_B - rp;              // write parity (opposite)
    const char* hsr = (const char*)Hs + af_base + rp;
    char* hsw = (char*)Hs + hw_base + wp;

    // ---- phase 1: gates i (regs) and g (LDS) ----
    f32x4 a0 = {0.f, 0.f, 0.f, 0.f}, a2 = a0;
#pragma unroll
    for (int ks = 0; ks < 8; ++ks) {
      bf16x8 af = *(const bf16x8*)(hsr + ks * 64);
      bf16x8 w2 = *(const bf16x8*)(wlds + ks * 512);
      a0 = __builtin_amdgcn_mfma_f32_16x16x32_bf16(af, wf0[ks], a0, 0, 0, 0);
      a2 = __builtin_amdgcn_mfma_f32_16x16x32_bf16(af, w2, a2, 0, 0, 0);
    }

    // ---- mid-step prefetch of next step's xg (hidden under phase2+epilogue) ----
    pxg += (size_t)((s + 1 < Ci) ? 16 * 1024 * 16 : 0);
    uint4 xb0 = *(const uint4*)pxg;
    uint4 xb1 = *(const uint4*)(pxg + 8);

    // ---- sigma(i)*tanh(g), fused rcp: (e_g-1) * rcp((1+e_i)(e_g+1)) ----
    const unsigned short* xv0 = (const unsigned short*)&xa0;  // gates i,f
    const unsigned short* xv1 = (const unsigned short*)&xa1;  // gates g,o
    float ig[4];
#pragma unroll
    for (int r = 0; r < 4; ++r) {
      float zi = a0[r] + bf2f(xv0[r]);       // log2 units
      float zg = a2[r] + bf2f(xv1[r]);       // 2*log2 units
      float ei = exp2_hw(-zi);
      float eg = exp2_hw(zg);
      ig[r] = (eg - 1.0f) * rcp_hw((1.0f + ei) * (eg + 1.0f));
    }

    // ---- phase 2: gates f (regs) and o (L2 stream) ----
    f32x4 a1 = {0.f, 0.f, 0.f, 0.f}, a3 = a1;
#pragma unroll
    for (int ks = 0; ks < 8; ++ks) {
      bf16x8 af = *(const bf16x8*)(hsr + ks * 64);
      bf16x8 w3 = *(const bf16x8*)(wr3 + ks * 32);
      a1 = __builtin_amdgcn_mfma_f32_16x16x32_bf16(af, wf1[ks], a1, 0, 0, 0);
      a3 = __builtin_amdgcn_mfma_f32_16x16x32_bf16(af, w3, a3, 0, 0, 0);
    }

    // ---- c/h epilogue: c = sigma(f)*c + ig ; h = sigma(o)*tanh(c) fused ----
#pragma unroll
    for (int r = 0; r < 4; ++r) {
      float zf = a1[r] + bf2f(xv0[4 + r]);
      float zo = a3[r] + bf2f(xv1[4 + r]);
      float ef = exp2_hw(-zf);
      float c = fmaf(creg[r], rcp_hw(1.0f + ef), ig[r]);
      creg[r] = c;
      float eo = exp2_hw(-zo);
      float ec = exp2_hw(fminf(c * TWO_LOG2E, 126.0f));  // clamp: no inf -> no NaN
      float h = (ec - 1.0f) * rcp_hw((1.0f + eo) * (ec + 1.0f));
      hv[r] = h;
      *(unsigned short*)(hsw + r * (PH * 2)) = f2bf(h);
    }
    xa0 = xb0;
    xa1 = xb1;
    __syncthreads();
  }

  // persist state; final output on last chunk
#pragma unroll
  for (int r = 0; r < 4; ++r) {
    const size_t gidx = (size_t)(b0 + quad * 4 + r) * H_SZ + jcol;
    h_st[gidx] = f2bf(hv[r]);
    c_st[gidx] = creg[r];
  }
  if (t0 + Ci == T_STEPS) {
#pragma unroll
    for (int r = 0; r < 4; ++r) {
      const size_t gidx = (size_t)(b0 + quad * 4 + r) * H_SZ + jcol;
      out[gidx] = hv[r];
      out[(size_t)B_SZ * H_SZ + gidx] = creg[r];
    }
  }
}

extern "C" void kernel_launch(void* const* d_in, const int* in_sizes, int n_in,
                              void* d_out, int out_size, void* d_ws, size_t ws_size,
                              hipStream_t stream) {
  const int* enc = (const int*)d_in[0];
  const float* h0 = (const float*)d_in[1];
  const float* c0 = (const float*)d_in[2];
  const float* embed = (const float*)d_in[3];
  const float* W_ih = (const float*)d_in[4];
  const float* W_hh = (const float*)d_in[5];
  const float* b_ih = (const float*)d_in[6];
  const float* b_hh = (const float*)d_in[7];
  float* out = (float*)d_out;

  char* ws = (char*)d_ws;
  unsigned short* Wih_bf = (unsigned short*)(ws);                  // 512 KB
  unsigned short* Whh_bf = (unsigned short*)(ws + (512 << 10));    // 512 KB
  float* bias = (float*)(ws + (1024 << 10));                       // 4 KB
  unsigned short* h_st = (unsigned short*)(ws + (1028 << 10));     // 128 KB
  float* c_st = (float*)(ws + (1156 << 10));                       // 256 KB
  const size_t fixed = (size_t)(1412) << 10;
  unsigned short* xg = (unsigned short*)(ws + fixed);

  const size_t per_step = (size_t)B_SZ * G4H * 2;  // 512 KB per timestep (bf16)
  int C = 1;
  if (ws_size > fixed + per_step) {
    size_t c = (ws_size - fixed) / per_step;
    C = (c > T_STEPS) ? T_STEPS : (int)c;
  }

  prep_kernel<<<dim3(256), dim3(256), 0, stream>>>(h0, c0, W_ih, W_hh, b_ih, b_hh,
                                                   Wih_bf, Whh_bf, bias, h_st, c_st);
  for (int t0 = 0; t0 < T_STEPS; t0 += C) {
    int Ci = (T_STEPS - t0 < C) ? (T_STEPS - t0) : C;
    xgate_kernel<<<dim3(Ci * 4), dim3(256), 0, stream>>>(enc, embed, Wih_bf, bias,
                                                         xg, t0, Ci);
    lstm_kernel<<<dim3(16), dim3(1024), 0, stream>>>(Whh_bf, xg, h_st, c_st,
                                                     out, t0, Ci);
  }
}